// Round 11
// baseline (204.989 us; speedup 1.0000x reference)
//
#include <hip/hip_runtime.h>
#include <hip/hip_bf16.h>
#include <math.h>

// Problem constants (B=8, T=1024, C=768, 12 heads, hd=64)
constexpr int Bsz  = 8;
constexpr int Tseq = 1024;
constexpr int Cdim = 768;
constexpr int NH   = 12;
constexpr int HD   = 64;
constexpr int Mrows = Bsz * Tseq;   // 8192
constexpr int C3    = 3 * Cdim;     // 2304

using short8  = __attribute__((ext_vector_type(8))) short;
using s4v     = __attribute__((ext_vector_type(4))) short;
using floatx4 = __attribute__((ext_vector_type(4))) float;
using uintx4  = __attribute__((ext_vector_type(4))) unsigned int;

__device__ __forceinline__ unsigned short f32_to_bf16_rn(float f) {
    unsigned int u = __float_as_uint(f);
    unsigned int r = u + 0x7FFFu + ((u >> 16) & 1u);
    return (unsigned short)(r >> 16);
}
// Packed f32x2 -> bf16x2 via the VENDOR header (compiler owns instruction
// selection + operand order). R12-R15 post-mortem: hand-written
// v_cvt_pk_bf16_f32 asm mis-places operands. Do NOT hand-write cvt_pk.
__device__ __forceinline__ unsigned pack_bf16x2_rn(float a, float b) {
    float2 f2; f2.x = a; f2.y = b;
    __hip_bfloat162 h = __float22bfloat162_rn(f2);
    unsigned r;
    __builtin_memcpy(&r, &h, sizeof(r));
    return r;
}
__device__ __forceinline__ short8 lds_ld8(const unsigned short* p) {
    s4v a = *(const s4v*)p;
    s4v b = *(const s4v*)(p + 4);
    return __builtin_shufflevector(a, b, 0, 1, 2, 3, 4, 5, 6, 7);
}
__device__ __forceinline__ void lds_st8(unsigned short* p, short8 v) {
    *(s4v*)p       = __builtin_shufflevector(v, v, 0, 1, 2, 3);
    *(s4v*)(p + 4) = __builtin_shufflevector(v, v, 4, 5, 6, 7);
}

#define GLOAD_LDS16(g, l) __builtin_amdgcn_global_load_lds(                    \
    (const __attribute__((address_space(1))) void*)(g),                        \
    (__attribute__((address_space(3))) void*)(l), 16, 0, 0)

#define WAITVM0 asm volatile("s_waitcnt vmcnt(0)" ::: "memory")

// ---------------------------------------------------------------------------
// fp32 -> bf16 (round-to-nearest), vectorized.
// ---------------------------------------------------------------------------
__global__ __launch_bounds__(256)
void to_bf16(const float* __restrict__ in, unsigned short* __restrict__ out, int n4)
{
    int t = blockIdx.x * blockDim.x + threadIdx.x;
    if (t >= n4) return;
    float4 v = ((const float4*)in)[t];
    ushort4 o;
    o.x = f32_to_bf16_rn(v.x);
    o.y = f32_to_bf16_rn(v.y);
    o.z = f32_to_bf16_rn(v.z);
    o.w = f32_to_bf16_rn(v.w);
    ((ushort4*)out)[t] = o;
}

// ---------------------------------------------------------------------------
// Transpose fp32 [K][N] -> bf16 [N][K].
// ---------------------------------------------------------------------------
__global__ __launch_bounds__(256)
void transpose_bf16(const float* __restrict__ in, unsigned short* __restrict__ out,
                    int K, int N)
{
    __shared__ float tile[32][33];
    const int k0 = blockIdx.y * 32, n0 = blockIdx.x * 32;
    const int tx = threadIdx.x & 31, ty = threadIdx.x >> 5;
    #pragma unroll
    for (int r = ty; r < 32; r += 8)
        tile[r][tx] = in[(size_t)(k0 + r) * N + n0 + tx];
    __syncthreads();
    #pragma unroll
    for (int r = ty; r < 32; r += 8)
        out[(size_t)(n0 + r) * K + k0 + tx] = f32_to_bf16_rn(tile[tx][r]);
}

// ---------------------------------------------------------------------------
// R17 qkv GEMM body (verified): BM=128 x BN=256, BK=32, 4 waves, 72 KB LDS,
// 2 blocks/CU, fine-phase counted-vmcnt pipeline (6 loads/tile, distance 2,
// vmcnt(6) steady, vmcnt(0) only at kt==NI-2). UNCHANGED this round.
// ---------------------------------------------------------------------------
template<bool HM, bool B16>
__device__ __forceinline__ void gemm_body_128x256(
    const unsigned short* __restrict__ A_g,
    const unsigned short* __restrict__ B_g,
    const float* __restrict__ bias,
    void* __restrict__ Cout,
    const int row0, const int col0, const int K, const int N,
    unsigned short* lds)
{
    constexpr int BK   = 32;
    constexpr int ABUF = 4096;           // ushorts: A 128x32
    constexpr int BUFS = 12288;          // A 4096 + B 8192 per buffer

    const int tid  = threadIdx.x;        // 0..255
    const int wave = tid >> 6;           // 0..3  (N quarter)
    const int lane = tid & 63;
    const int lm   = lane & 15;
    const int quad = lane >> 4;
    const int NI   = K / BK;             // 24
    const int sq8  = (quad ^ ((lm ^ (lm >> 2)) & 3)) * 8;
    const int sr   = tid >> 2;           // staging row within 64-row group
    const int sq   = tid & 3;            // staging chunk

    floatx4 acc[8][4] = {};

    auto stageA = [&](int buf, int k0) {
        #pragma unroll
        for (int s = 0; s < 2; ++s) {    // 128 rows x 4 chunks / 256 thr = 2
            const int r  = s * 64 + sr;
            const int gc = ((sq ^ ((r ^ (r >> 2)) & 3)) << 3);
            if constexpr (HM) {
                const int head = k0 >> 6;                 // HD=64, BK=32 in-head
                const int off  = (k0 & 63) + gc;
                GLOAD_LDS16(A_g + (size_t)head * (Mrows * HD) +
                            (size_t)(row0 + r) * HD + off,
                            lds + buf * BUFS + r * 32 + sq * 8);
            } else {
                GLOAD_LDS16(A_g + (size_t)(row0 + r) * K + k0 + gc,
                            lds + buf * BUFS + r * 32 + sq * 8);
            }
        }
    };
    auto stageB = [&](int buf, int k0) {
        #pragma unroll
        for (int s = 0; s < 4; ++s) {    // 256 rows x 4 chunks / 256 thr = 4
            const int r  = s * 64 + sr;
            const int gc = ((sq ^ ((r ^ (r >> 2)) & 3)) << 3);
            GLOAD_LDS16(B_g + (size_t)(col0 + r) * K + k0 + gc,
                        lds + buf * BUFS + ABUF + r * 32 + sq * 8);
        }
    };

    // prologue: tile 0 -> buf0, tile 1 -> buf1  (12 loads in flight)
    stageA(0, 0);  stageB(0, 0);
    stageA(1, BK); stageB(1, BK);
    asm volatile("s_waitcnt vmcnt(6)" ::: "memory");   // tile 0 landed
    __builtin_amdgcn_s_barrier();

    short8 af[4], bf[4];
    int cur = 0;
    for (int kt = 0; kt < NI; ++kt) {
        const unsigned short* bufA = lds + cur * BUFS;
        const unsigned short* bufB = bufA + ABUF;
        const int  stg  = (cur + 2 >= 3) ? cur - 1 : cur + 2;
        const int  k2   = (kt + 2) * BK;
        const bool doSt = (kt + 2 < NI);

        // ---- phase 0: row half 0, all N ----
        #pragma unroll
        for (int i = 0; i < 4; ++i)
            af[i] = *(const short8*)(bufA + (i * 16 + lm) * 32 + sq8);
        #pragma unroll
        for (int j = 0; j < 4; ++j)
            bf[j] = *(const short8*)(bufB + (wave * 64 + j * 16 + lm) * 32 + sq8);
        if (doSt) stageA(stg, k2);
        __builtin_amdgcn_s_barrier();
        __builtin_amdgcn_s_setprio(1);
        #pragma unroll
        for (int i = 0; i < 4; ++i)
            #pragma unroll
            for (int j = 0; j < 4; ++j)
                acc[i][j] = __builtin_amdgcn_mfma_f32_16x16x32_bf16(af[i], bf[j], acc[i][j], 0, 0, 0);
        __builtin_amdgcn_s_setprio(0);
        __builtin_amdgcn_s_barrier();

        // ---- phase 1: row half 1 (bf reused) ----
        #pragma unroll
        for (int i = 0; i < 4; ++i)
            af[i] = *(const short8*)(bufA + ((4 + i) * 16 + lm) * 32 + sq8);
        if (doSt) stageB(stg, k2);
        __builtin_amdgcn_s_barrier();
        __builtin_amdgcn_s_setprio(1);
        #pragma unroll
        for (int i = 0; i < 4; ++i)
            #pragma unroll
            for (int j = 0; j < 4; ++j)
                acc[4 + i][j] = __builtin_amdgcn_mfma_f32_16x16x32_bf16(af[i], bf[j], acc[4 + i][j], 0, 0, 0);
        __builtin_amdgcn_s_setprio(0);
        // counted wait: retire tile kt+1's 6 loads, keep kt+2's in flight.
        if (kt == NI - 2) { WAITVM0; }
        else if (kt < NI - 2) {
            asm volatile("s_waitcnt vmcnt(6)" ::: "memory");
        }
        __builtin_amdgcn_s_barrier();

        cur = (cur == 2) ? 0 : cur + 1;
    }
    asm volatile("" ::: "memory");

    if constexpr (B16) {
        // ---- coalesced bf16 epilogue: per-wave LDS bounce, PADDED stride 68.
        unsigned short* Cb   = (unsigned short*)Cout;
        unsigned short* wbuf = lds + (NI % 3) * BUFS + wave * 1088;   // 16 x 68
        float bvj[4];
        #pragma unroll
        for (int j = 0; j < 4; ++j) bvj[j] = bias[col0 + wave * 64 + j * 16 + lm];
        #pragma unroll
        for (int i = 0; i < 8; ++i) {
            #pragma unroll
            for (int j = 0; j < 4; ++j) {
                #pragma unroll
                for (int r = 0; r < 4; ++r)
                    wbuf[(quad * 4 + r) * 68 + j * 16 + lm] = f32_to_bf16_rn(acc[i][j][r] + bvj[j]);
            }
            asm volatile("s_waitcnt lgkmcnt(0)" ::: "memory");  // cross-lane RAW
            #pragma unroll
            for (int p = 0; p < 2; ++p) {
                const int lrow  = p * 8 + (lane >> 3);
                const int lcol8 = (lane & 7) * 8;
                short8 v = lds_ld8(&wbuf[lrow * 68 + lcol8]);
                *(short8*)(Cb + (size_t)(row0 + i * 16 + lrow) * N +
                           col0 + wave * 64 + lcol8) = v;
            }
            asm volatile("s_waitcnt lgkmcnt(0)" ::: "memory");  // WAR before next i
        }
    } else {
        // ---- fp32 direct epilogue ----
        float* C = (float*)Cout;
        #pragma unroll
        for (int j = 0; j < 4; ++j) {
            const int col = col0 + wave * 64 + j * 16 + lm;
            const float bv = bias[col];
            #pragma unroll
            for (int i = 0; i < 8; ++i) {
                const int rowb = row0 + i * 16 + quad * 4;
                #pragma unroll
                for (int r = 0; r < 4; ++r)
                    C[(size_t)(rowb + r) * N + col] = acc[i][j][r] + bv;
            }
        }
    }
}

// qkv: 64 row-tiles x 9 col-tiles = 576 blocks (%8==0), bijective XCD chunk.
__global__ __launch_bounds__(256, 2)
void gemm_qkv128(const unsigned short* __restrict__ A_g,
                 const unsigned short* __restrict__ B_g,
                 const float* __restrict__ bias,
                 unsigned short* __restrict__ Cb)
{
    __shared__ __align__(16) unsigned short lds[3 * 12288];   // 72 KB
    const int bid = blockIdx.x;
    const int sid = (bid & 7) * 72 + (bid >> 3);              // 576/8 = 72
    const int by  = sid & 63;                                  // row tile
    const int bx  = sid >> 6;                                  // col tile 0..8
    gemm_body_128x256<false, true>(A_g, B_g, bias, Cb,
                                   by * 128, bx * 256, Cdim, C3, lds);
}

// ---------------------------------------------------------------------------
// R18 proj GEMM: BM=128 x BN=128, BK=32, 4 waves (2x2, each 64x64), 48 KB LDS
// (3 x 16 KB) -> 3 BLOCKS/CU.  Grid 64x6 = 384 blocks (%8==0): every CU gets
// work, most get 2+ resident blocks to overlap the barrier/vmcnt stalls that
// made the 192-block 0.75/CU version ~50 us for 9.7 GFLOP.
// Same fine-phase counted-vmcnt ledger: 4 loads/tile, prefetch distance 2,
// vmcnt(4) steady, vmcnt(0) only at kt==NI-2. Head-major A (BK=32 in-head).
// K-order identical -> bit-identical output.
// ---------------------------------------------------------------------------
__global__ __launch_bounds__(256, 3)
void gemm_proj128sq(const unsigned short* __restrict__ AO_g,
                    const unsigned short* __restrict__ B_g,
                    const float* __restrict__ bias,
                    float* __restrict__ C)
{
    constexpr int BK   = 32;
    constexpr int K    = Cdim, N = Cdim;
    constexpr int ABUF = 4096;           // ushorts: A 128x32
    constexpr int BUFS = 8192;           // A 4096 + B 4096 per buffer
    __shared__ __align__(16) unsigned short lds[3 * BUFS];   // 48 KB

    const int tid  = threadIdx.x;
    const int wave = tid >> 6;
    const int lane = tid & 63;
    const int lm   = lane & 15;
    const int quad = lane >> 4;
    const int wy   = wave >> 1, wx = wave & 1;
    const int bid  = blockIdx.x;
    const int sid  = (bid & 7) * 48 + (bid >> 3);            // 384/8 = 48
    const int row0 = (sid & 63) * 128;
    const int col0 = (sid >> 6) * 128;                        // 0..5
    const int NI   = K / BK;             // 24
    const int sq8  = (quad ^ ((lm ^ (lm >> 2)) & 3)) * 8;
    const int sr   = tid >> 2;
    const int sq   = tid & 3;

    floatx4 acc[4][4] = {};

    auto stageA = [&](int buf, int k0) {
        #pragma unroll
        for (int s = 0; s < 2; ++s) {
            const int r  = s * 64 + sr;
            const int gc = ((sq ^ ((r ^ (r >> 2)) & 3)) << 3);
            const int head = k0 >> 6;
            const int off  = (k0 & 63) + gc;
            GLOAD_LDS16(AO_g + (size_t)head * (Mrows * HD) +
                        (size_t)(row0 + r) * HD + off,
                        lds + buf * BUFS + r * 32 + sq * 8);
        }
    };
    auto stageB = [&](int buf, int k0) {
        #pragma unroll
        for (int s = 0; s < 2; ++s) {
            const int r  = s * 64 + sr;
            const int gc = ((sq ^ ((r ^ (r >> 2)) & 3)) << 3);
            GLOAD_LDS16(B_g + (size_t)(col0 + r) * K + k0 + gc,
                        lds + buf * BUFS + ABUF + r * 32 + sq * 8);
        }
    };

    // prologue: tile 0 -> buf0, tile 1 -> buf1  (8 loads in flight)
    stageA(0, 0);  stageB(0, 0);
    stageA(1, BK); stageB(1, BK);
    asm volatile("s_waitcnt vmcnt(4)" ::: "memory");   // tile 0 landed
    __builtin_amdgcn_s_barrier();

    short8 af[4], bf[4];
    int cur = 0;
    for (int kt = 0; kt < NI; ++kt) {
        const unsigned short* bufA = lds + cur * BUFS;
        const unsigned short* bufB = bufA + ABUF;
        const int  stg  = (cur + 2 >= 3) ? cur - 1 : cur + 2;
        const int  k2   = (kt + 2) * BK;
        const bool doSt = (kt + 2 < NI);

        // ---- phase 0: all A frags + N half 0 ----
        #pragma unroll
        for (int i = 0; i < 4; ++i)
            af[i] = *(const short8*)(bufA + (wy * 64 + i * 16 + lm) * 32 + sq8);
        #pragma unroll
        for (int j = 0; j < 2; ++j)
            bf[j] = *(const short8*)(bufB + (wx * 64 + j * 16 + lm) * 32 + sq8);
        if (doSt) stageA(stg, k2);
        __builtin_amdgcn_s_barrier();
        __builtin_amdgcn_s_setprio(1);
        #pragma unroll
        for (int i = 0; i < 4; ++i)
            #pragma unroll
            for (int j = 0; j < 2; ++j)
                acc[i][j] = __builtin_amdgcn_mfma_f32_16x16x32_bf16(af[i], bf[j], acc[i][j], 0, 0, 0);
        __builtin_amdgcn_s_setprio(0);
        __builtin_amdgcn_s_barrier();

        // ---- phase 1: N half 1 (af reused) ----
        #pragma unroll
        for (int j = 2; j < 4; ++j)
            bf[j] = *(const short8*)(bufB + (wx * 64 + j * 16 + lm) * 32 + sq8);
        if (doSt) stageB(stg, k2);
        __builtin_amdgcn_s_barrier();
        __builtin_amdgcn_s_setprio(1);
        #pragma unroll
        for (int i = 0; i < 4; ++i)
            #pragma unroll
            for (int j = 2; j < 4; ++j)
                acc[i][j] = __builtin_amdgcn_mfma_f32_16x16x32_bf16(af[i], bf[j], acc[i][j], 0, 0, 0);
        __builtin_amdgcn_s_setprio(0);
        // counted wait: retire tile kt+1's 4 loads, keep kt+2's in flight.
        if (kt == NI - 2) { WAITVM0; }
        else if (kt < NI - 2) {
            asm volatile("s_waitcnt vmcnt(4)" ::: "memory");
        }
        __builtin_amdgcn_s_barrier();

        cur = (cur == 2) ? 0 : cur + 1;
    }
    asm volatile("" ::: "memory");

    // ---- fp32 direct epilogue ----
    #pragma unroll
    for (int j = 0; j < 4; ++j) {
        const int col = col0 + wx * 64 + j * 16 + lm;
        const float bv = bias[col];
        #pragma unroll
        for (int i = 0; i < 4; ++i) {
            const int rowb = row0 + wy * 64 + i * 16 + quad * 4;
            #pragma unroll
            for (int r = 0; r < 4; ++r)
                C[(size_t)(rowb + r) * N + col] = acc[i][j][r] + bv;
        }
    }
}

// ---------------------------------------------------------------------------
// Pure-bf16 MFMA flash attention, R16 (VERIFIED): register-resident P.
//   K rows at swapped LDS positions (bits 3<->4); P redistribution = one
//   lane-bit4 <-> slot-bit1 exchange (4 shfl_xor(16) + selects per mt);
//   vendor pack_bf16x2_rn; mask-skip; 35.3 KB LDS, 3 blocks/CU. UNCHANGED.
// ---------------------------------------------------------------------------
__global__ __launch_bounds__(256, 3)
void attn_bf16(const unsigned short* __restrict__ qkv,
               const int* __restrict__ mask,
               unsigned short* __restrict__ outh)
{
    constexpr int LDW = 68;
    constexpr int NT  = Tseq / 64;     // 16 K-tiles
    __shared__ __align__(16) unsigned short Kh[2][64 * LDW];
    __shared__ __align__(16) unsigned short Vh[2][64 * LDW];   // V^T [d][k]
    __shared__ float maskadd[2][64];   // PHYSICAL (swapped) index
    __shared__ int   mflag[2];         // 1 = no masked keys in this tile

    const int tid  = threadIdx.x;
    const int wave = tid >> 6;
    const int lane = tid & 63;
    const int lm   = lane & 15;
    const int quad = lane >> 4;
    const int idx  = blockIdx.x;
    const int bh   = idx % (Bsz * NH);
    const int qb   = idx / (Bsz * NH);
    const int b    = bh / NH;
    const int h    = bh % NH;
    const int q0   = qb * 128;
    const float scale = 0.125f;        // 1/sqrt(64)

    // Q fragments (B-layout: n=lm, k=quad*8+j) straight from global
    short8 qf[2][2];
    #pragma unroll
    for (int mt = 0; mt < 2; ++mt) {
        const size_t qrow = (size_t)(b * Tseq + q0 + wave * 32 + mt * 16 + lm) * C3 + h * HD;
        #pragma unroll
        for (int kf = 0; kf < 2; ++kf)
            qf[mt][kf] = *(const short8*)(qkv + qrow + kf * 32 + quad * 8);
    }

    const int tr0 = (tid & 31) * 2;    // TRUE k-row pair (global load, V col)
    const int sc  = (tid >> 5) * 8;    // 8 dims
    // physical K position: swap bits 3<->4 of the row index
    const int ps0 = (tr0 & 0x27) | ((tr0 & 0x10) >> 1) | ((tr0 & 0x08) << 1);
    const int smi = (tid & 0x27) | ((tid & 0x10) >> 1) | ((tid & 0x08) << 1);

    short8 kh0, kh1, vh0, vh1;
    float  mreg = 0.f;

    // --- prefetch + store tile 0 into buf 0 ---
    {
        const size_t g0 = (size_t)(b * Tseq + tr0) * C3 + Cdim + h * HD + sc;
        kh0 = *(const short8*)(qkv + g0);
        kh1 = *(const short8*)(qkv + g0 + C3);
        vh0 = *(const short8*)(qkv + g0 + Cdim);
        vh1 = *(const short8*)(qkv + g0 + Cdim + C3);
        lds_st8(&Kh[0][ps0 * LDW + sc], kh0);
        lds_st8(&Kh[0][(ps0 + 1) * LDW + sc], kh1);
        #pragma unroll
        for (int i = 0; i < 8; ++i) {
            unsigned int pv = (unsigned int)(unsigned short)vh0[i] |
                              ((unsigned int)(unsigned short)vh1[i] << 16);
            *(unsigned int*)&Vh[0][(sc + i) * LDW + tr0] = pv;
        }
        if (tid < 64) {
            mreg = (mask[b * Tseq + tid] == 0) ? -1e30f : 0.0f;
            const int f = __all(mreg == 0.0f);
            maskadd[0][smi] = mreg;
            if (tid == 0) mflag[0] = f;
        }
    }
    __syncthreads();

    floatx4 O[2][4] = {};              // [m][d-tile]; lane: q=lm, d=quad*4+r
    float lsum[2] = {0.f, 0.f};

    for (int kt = 0; kt < NT; ++kt) {
        const int cur = kt & 1;
        const int nxt = cur ^ 1;
        const unsigned short* Khc = Kh[cur];
        const unsigned short* Vhc = Vh[cur];

        // ---- issue prefetch for tile kt+1 early (latency behind compute) ----
        if (kt + 1 < NT) {
            const size_t g0 = (size_t)(b * Tseq + (kt + 1) * 64 + tr0) * C3 + Cdim + h * HD + sc;
            kh0 = *(const short8*)(qkv + g0);
            kh1 = *(const short8*)(qkv + g0 + C3);
            vh0 = *(const short8*)(qkv + g0 + Cdim);
            vh1 = *(const short8*)(qkv + g0 + Cdim + C3);
            if (tid < 64) mreg = (mask[b * Tseq + (kt + 1) * 64 + tid] == 0) ? -1e30f : 0.0f;
        }

        // ---- S^T = K Q^T : D[pos][q], lane: q=lm, pos=quad*4+r (permuted k) ----
        floatx4 S[2][4] = {};
        #pragma unroll
        for (int kf = 0; kf < 2; ++kf) {
            short8 kh[4];
            #pragma unroll
            for (int nt = 0; nt < 4; ++nt)
                kh[nt] = lds_ld8(&Khc[(nt * 16 + lm) * LDW + kf * 32 + quad * 8]);
            #pragma unroll
            for (int mt = 0; mt < 2; ++mt)
                #pragma unroll
                for (int nt = 0; nt < 4; ++nt)
                    S[mt][nt] = __builtin_amdgcn_mfma_f32_16x16x32_bf16(kh[nt], qf[mt][kf], S[mt][nt], 0, 0, 0);
        }

        const int nomask = mflag[cur];   // block-uniform

        // ---- softmax numerator -> packed bf16 pairs in registers ----
        unsigned X[2][8];
        if (nomask) {
            #pragma unroll
            for (int mt = 0; mt < 2; ++mt) {
                #pragma unroll
                for (int nt = 0; nt < 4; ++nt) {
                    float p0 = __expf(S[mt][nt][0] * scale);
                    float p1 = __expf(S[mt][nt][1] * scale);
                    float p2 = __expf(S[mt][nt][2] * scale);
                    float p3 = __expf(S[mt][nt][3] * scale);
                    lsum[mt] += p0; lsum[mt] += p1;
                    lsum[mt] += p2; lsum[mt] += p3;
                    X[mt][nt * 2 + 0] = pack_bf16x2_rn(p0, p1);
                    X[mt][nt * 2 + 1] = pack_bf16x2_rn(p2, p3);
                }
            }
        } else {
            float madd[4][4];
            #pragma unroll
            for (int nt = 0; nt < 4; ++nt)
                #pragma unroll
                for (int r = 0; r < 4; ++r)
                    madd[nt][r] = maskadd[cur][nt * 16 + quad * 4 + r];  // physical
            #pragma unroll
            for (int mt = 0; mt < 2; ++mt) {
                #pragma unroll
                for (int nt = 0; nt < 4; ++nt) {
                    float p0 = __expf(S[mt][nt][0] * scale + madd[nt][0]);
                    float p1 = __expf(S[mt][nt][1] * scale + madd[nt][1]);
                    float p2 = __expf(S[mt][nt][2] * scale + madd[nt][2]);
                    float p3 = __expf(S[mt][nt][3] * scale + madd[nt][3]);
                    lsum[mt] += p0; lsum[mt] += p1;
                    lsum[mt] += p2; lsum[mt] += p3;
                    X[mt][nt * 2 + 0] = pack_bf16x2_rn(p0, p1);
                    X[mt][nt * 2 + 1] = pack_bf16x2_rn(p2, p3);
                }
            }
        }

        // ---- quad exchange: lane-bit4 <-> slot-bit1.
        const bool qodd = (quad & 1);
        short8 pf[2][2];
        #pragma unroll
        for (int mt = 0; mt < 2; ++mt) {
            #pragma unroll
            for (int pr = 0; pr < 4; ++pr) {
                const int a  = (pr & 1) | ((pr & 2) << 1);   // 0,1,4,5
                const int b2 = a + 2;
                unsigned t = qodd ? X[mt][a] : X[mt][b2];
                t = (unsigned)__shfl_xor((int)t, 16);
                X[mt][a]  = qodd ? t : X[mt][a];
                X[mt][b2] = qodd ? X[mt][b2] : t;
            }
            uintx4 u0 = {X[mt][0], X[mt][1], X[mt][2], X[mt][3]};
            uintx4 u1 = {X[mt][4], X[mt][5], X[mt][6], X[mt][7]};
            __builtin_memcpy(&pf[mt][0], &u0, 16);
            __builtin_memcpy(&pf[mt][1], &u1, 16);
        }

        // ---- O^T += V^T P^T (P in registers) ----
        #pragma unroll
        for (int kf = 0; kf < 2; ++kf) {
            #pragma unroll
            for (int dt = 0; dt < 4; ++dt) {
                short8 vh = lds_ld8(&Vhc[(dt * 16 + lm) * LDW + kf * 32 + quad * 8]);
                #pragma unroll
                for (int mt = 0; mt < 2; ++mt)
                    O[mt][dt] = __builtin_amdgcn_mfma_f32_16x16x32_bf16(vh, pf[mt][kf], O[mt][dt], 0, 0, 0);
            }
        }

        // ---- store prefetched tile into the other buffer ----
        if (kt + 1 < NT) {
            lds_st8(&Kh[nxt][ps0 * LDW + sc], kh0);
            lds_st8(&Kh[nxt][(ps0 + 1) * LDW + sc], kh1);
            #pragma unroll
            for (int i = 0; i < 8; ++i) {
                unsigned int pv = (unsigned int)(unsigned short)vh0[i] |
                                  ((unsigned int)(unsigned short)vh1[i] << 16);
                *(unsigned int*)&Vh[nxt][(sc + i) * LDW + tr0] = pv;
            }
            if (tid < 64) {
                const int f = __all(mreg == 0.0f);
                maskadd[nxt][smi] = mreg;
                if (tid == 0) mflag[nxt] = f;
            }
        }
        __syncthreads();               // single barrier: orders store->read
    }

    // ---- final l reduction across quads, normalize, head-major write ----
    #pragma unroll
    for (int mt = 0; mt < 2; ++mt) {
        lsum[mt] += __shfl_xor(lsum[mt], 16);
        lsum[mt] += __shfl_xor(lsum[mt], 32);
        const float inv_l = 1.0f / lsum[mt];
        const size_t row = (size_t)h * (Mrows * HD) +
                           (size_t)(b * Tseq + q0 + wave * 32 + mt * 16 + lm) * HD;
        #pragma unroll
        for (int dt = 0; dt < 4; ++dt) {
            ushort4 hv;
            unsigned short* hp = &hv.x;
            #pragma unroll
            for (int r = 0; r < 4; ++r)
                hp[r] = f32_to_bf16_rn(O[mt][dt][r] * inv_l);
            *(ushort4*)(outh + row + dt * 16 + quad * 4) = hv;
        }
    }
}

// ---------------------------------------------------------------------------
extern "C" void kernel_launch(void* const* d_in, const int* in_sizes, int n_in,
                              void* d_out, int out_size, void* d_ws, size_t ws_size,
                              hipStream_t stream)
{
    const float* x      = (const float*)d_in[0];
    const int*   mask   = (const int*)  d_in[1];
    const float* W_attn = (const float*)d_in[2];
    const float* b_attn = (const float*)d_in[3];
    const float* W_proj = (const float*)d_in[4];
    const float* b_proj = (const float*)d_in[5];
    float* out = (float*)d_out;

    // workspace (~55 MB)
    unsigned short* xh    = (unsigned short*)d_ws;               // [8192][768]
    unsigned short* wat_h = xh    + (size_t)Mrows * Cdim;        // W_attn^T
    unsigned short* wpt_h = wat_h + (size_t)C3 * Cdim;           // W_proj^T
    unsigned short* qkvh  = wpt_h + (size_t)Cdim * Cdim;         // [8192][2304]
    unsigned short* aoh   = xh;    // reuse: xh dead after gemm1; [12][8192][64]

    dim3 blk(256);

    to_bf16<<<dim3(Mrows * Cdim / 4 / 256), blk, 0, stream>>>(x, xh, Mrows * Cdim / 4);
    transpose_bf16<<<dim3(C3 / 32, Cdim / 32), blk, 0, stream>>>(W_attn, wat_h, Cdim, C3);
    transpose_bf16<<<dim3(Cdim / 32, Cdim / 32), blk, 0, stream>>>(W_proj, wpt_h, Cdim, Cdim);

    // qkv = x @ W_attn + b_attn  (bf16 out): 64x9 = 576 uniform blocks, 2/CU
    gemm_qkv128<<<dim3(576), blk, 0, stream>>>(xh, wat_h, b_attn, qkvh);

    // attention -> head-major bf16
    attn_bf16<<<dim3((Tseq / 128) * Bsz * NH), blk, 0, stream>>>(qkvh, mask, aoh);

    // out = attnout @ W_proj + b_proj (fp32 out): 64x6 = 384 blocks, 3/CU cap
    gemm_proj128sq<<<dim3(384), blk, 0, stream>>>(aoh, wpt_h, b_proj, out);
}

// Round 12
// 200.699 us; speedup vs baseline: 1.0214x; 1.0214x over previous
//
#include <hip/hip_runtime.h>
#include <hip/hip_bf16.h>
#include <math.h>

// Problem constants (B=8, T=1024, C=768, 12 heads, hd=64)
constexpr int Bsz  = 8;
constexpr int Tseq = 1024;
constexpr int Cdim = 768;
constexpr int NH   = 12;
constexpr int HD   = 64;
constexpr int Mrows = Bsz * Tseq;   // 8192
constexpr int C3    = 3 * Cdim;     // 2304

using short8  = __attribute__((ext_vector_type(8))) short;
using s4v     = __attribute__((ext_vector_type(4))) short;
using floatx4 = __attribute__((ext_vector_type(4))) float;
using uintx4  = __attribute__((ext_vector_type(4))) unsigned int;

__device__ __forceinline__ unsigned short f32_to_bf16_rn(float f) {
    unsigned int u = __float_as_uint(f);
    unsigned int r = u + 0x7FFFu + ((u >> 16) & 1u);
    return (unsigned short)(r >> 16);
}
// Packed f32x2 -> bf16x2 via the VENDOR header (compiler owns instruction
// selection + operand order). R12-R15 post-mortem: hand-written
// v_cvt_pk_bf16_f32 asm mis-places operands. Do NOT hand-write cvt_pk.
__device__ __forceinline__ unsigned pack_bf16x2_rn(float a, float b) {
    float2 f2; f2.x = a; f2.y = b;
    __hip_bfloat162 h = __float22bfloat162_rn(f2);
    unsigned r;
    __builtin_memcpy(&r, &h, sizeof(r));
    return r;
}
__device__ __forceinline__ short8 lds_ld8(const unsigned short* p) {
    s4v a = *(const s4v*)p;
    s4v b = *(const s4v*)(p + 4);
    return __builtin_shufflevector(a, b, 0, 1, 2, 3, 4, 5, 6, 7);
}
__device__ __forceinline__ void lds_st8(unsigned short* p, short8 v) {
    *(s4v*)p       = __builtin_shufflevector(v, v, 0, 1, 2, 3);
    *(s4v*)(p + 4) = __builtin_shufflevector(v, v, 4, 5, 6, 7);
}

#define GLOAD_LDS16(g, l) __builtin_amdgcn_global_load_lds(                    \
    (const __attribute__((address_space(1))) void*)(g),                        \
    (__attribute__((address_space(3))) void*)(l), 16, 0, 0)

#define WAITVM0 asm volatile("s_waitcnt vmcnt(0)" ::: "memory")

// ---------------------------------------------------------------------------
// R19 merged prep kernel: fp32->bf16 cast of x  +  both weight transposes,
// one dispatch (was 3). Block-uniform branch; concurrent execution of the
// three jobs removes 2 launch gaps and overlaps cast with transposes.
//   blocks [0,6144)        : cast x (8192x768 fp32 -> bf16), 4 elems/thread
//   blocks [6144,7872)     : transpose W_attn [768][2304] -> [2304][768]
//   blocks [7872,8448)     : transpose W_proj [768][768]  -> [768][768]
// ---------------------------------------------------------------------------
__global__ __launch_bounds__(256)
void prep_all(const float* __restrict__ x,      unsigned short* __restrict__ xh,
              const float* __restrict__ W_attn, unsigned short* __restrict__ wat_h,
              const float* __restrict__ W_proj, unsigned short* __restrict__ wpt_h)
{
    __shared__ float tile[32][33];
    const int bid = blockIdx.x;
    if (bid < 6144) {
        const int t = bid * 256 + threadIdx.x;      // 6144*256 == Mrows*Cdim/4
        float4 v = ((const float4*)x)[t];
        ushort4 o;
        o.x = f32_to_bf16_rn(v.x);
        o.y = f32_to_bf16_rn(v.y);
        o.z = f32_to_bf16_rn(v.z);
        o.w = f32_to_bf16_rn(v.w);
        ((ushort4*)xh)[t] = o;
        return;
    }
    const float* in; unsigned short* out; int N, bx, by;
    if (bid < 6144 + 1728) {                        // W_attn: 72 x 24 tiles
        const int r = bid - 6144;
        in = W_attn; out = wat_h; N = C3;
        bx = r % 72; by = r / 72;
    } else {                                        // W_proj: 24 x 24 tiles
        const int r = bid - 7872;
        in = W_proj; out = wpt_h; N = Cdim;
        bx = r % 24; by = r / 24;
    }
    const int K  = Cdim;
    const int k0 = by * 32, n0 = bx * 32;
    const int tx = threadIdx.x & 31, ty = threadIdx.x >> 5;
    #pragma unroll
    for (int r = ty; r < 32; r += 8)
        tile[r][tx] = in[(size_t)(k0 + r) * N + n0 + tx];
    __syncthreads();
    #pragma unroll
    for (int r = ty; r < 32; r += 8)
        out[(size_t)(n0 + r) * K + k0 + tx] = f32_to_bf16_rn(tile[tx][r]);
}

// ---------------------------------------------------------------------------
// R19 qkv GEMM body: BM=128 x BN=256, BK=32, 4 waves, 72 KB LDS, 2 blocks/CU.
// BARRIER DIET: 4 barriers/K-tile -> 1. Derivation (3-buffer rotation,
// stg=(kt+2)%3==(kt-1)%3):
//   WAR (stage@kt overwrites buffer read at kt-1): reads@kt-1 complete before
//     that wave's MFMA (compiler lgkmcnt), wave then reaches end-of-tile(kt-1)
//     barrier; stage@kt is issued after it. Safe.
//   RAW (reads@kt see stage@kt-2's gload_lds): vmcnt(6)@kt-1 retires all but
//     the newest 6 loads (= stage@kt-1), i.e. stage@kt-2 done; barrier
//     publishes across waves. Safe.
// The two mid-tile barriers protected nothing (own-wave ds_read->MFMA deps
// are lgkmcnt'd). Fine ds_read || stage || MFMA interleave retained (m196).
// Counted vmcnt(6) steady; vmcnt(0) only at kt==NI-2.
// ---------------------------------------------------------------------------
template<bool HM, bool B16>
__device__ __forceinline__ void gemm_body_128x256(
    const unsigned short* __restrict__ A_g,
    const unsigned short* __restrict__ B_g,
    const float* __restrict__ bias,
    void* __restrict__ Cout,
    const int row0, const int col0, const int K, const int N,
    unsigned short* lds)
{
    constexpr int BK   = 32;
    constexpr int ABUF = 4096;           // ushorts: A 128x32
    constexpr int BUFS = 12288;          // A 4096 + B 8192 per buffer

    const int tid  = threadIdx.x;        // 0..255
    const int wave = tid >> 6;           // 0..3  (N quarter)
    const int lane = tid & 63;
    const int lm   = lane & 15;
    const int quad = lane >> 4;
    const int NI   = K / BK;             // 24
    const int sq8  = (quad ^ ((lm ^ (lm >> 2)) & 3)) * 8;
    const int sr   = tid >> 2;           // staging row within 64-row group
    const int sq   = tid & 3;            // staging chunk

    floatx4 acc[8][4] = {};

    auto stageA = [&](int buf, int k0) {
        #pragma unroll
        for (int s = 0; s < 2; ++s) {    // 128 rows x 4 chunks / 256 thr = 2
            const int r  = s * 64 + sr;
            const int gc = ((sq ^ ((r ^ (r >> 2)) & 3)) << 3);
            if constexpr (HM) {
                const int head = k0 >> 6;                 // HD=64, BK=32 in-head
                const int off  = (k0 & 63) + gc;
                GLOAD_LDS16(A_g + (size_t)head * (Mrows * HD) +
                            (size_t)(row0 + r) * HD + off,
                            lds + buf * BUFS + r * 32 + sq * 8);
            } else {
                GLOAD_LDS16(A_g + (size_t)(row0 + r) * K + k0 + gc,
                            lds + buf * BUFS + r * 32 + sq * 8);
            }
        }
    };
    auto stageB = [&](int buf, int k0) {
        #pragma unroll
        for (int s = 0; s < 4; ++s) {    // 256 rows x 4 chunks / 256 thr = 4
            const int r  = s * 64 + sr;
            const int gc = ((sq ^ ((r ^ (r >> 2)) & 3)) << 3);
            GLOAD_LDS16(B_g + (size_t)(col0 + r) * K + k0 + gc,
                        lds + buf * BUFS + ABUF + r * 32 + sq * 8);
        }
    };

    // prologue: tile 0 -> buf0, tile 1 -> buf1  (12 loads in flight)
    stageA(0, 0);  stageB(0, 0);
    stageA(1, BK); stageB(1, BK);
    asm volatile("s_waitcnt vmcnt(6)" ::: "memory");   // tile 0 landed
    __builtin_amdgcn_s_barrier();

    short8 af[4], bf[4];
    int cur = 0;
    for (int kt = 0; kt < NI; ++kt) {
        const unsigned short* bufA = lds + cur * BUFS;
        const unsigned short* bufB = bufA + ABUF;
        const int  stg  = (cur + 2 >= 3) ? cur - 1 : cur + 2;
        const int  k2   = (kt + 2) * BK;
        const bool doSt = (kt + 2 < NI);

        // ---- half 0: ds_reads + stageA, then MFMA (no barrier) ----
        #pragma unroll
        for (int i = 0; i < 4; ++i)
            af[i] = *(const short8*)(bufA + (i * 16 + lm) * 32 + sq8);
        #pragma unroll
        for (int j = 0; j < 4; ++j)
            bf[j] = *(const short8*)(bufB + (wave * 64 + j * 16 + lm) * 32 + sq8);
        if (doSt) stageA(stg, k2);
        __builtin_amdgcn_s_setprio(1);
        #pragma unroll
        for (int i = 0; i < 4; ++i)
            #pragma unroll
            for (int j = 0; j < 4; ++j)
                acc[i][j] = __builtin_amdgcn_mfma_f32_16x16x32_bf16(af[i], bf[j], acc[i][j], 0, 0, 0);
        __builtin_amdgcn_s_setprio(0);

        // ---- half 1: ds_reads + stageB, then MFMA (bf reused) ----
        #pragma unroll
        for (int i = 0; i < 4; ++i)
            af[i] = *(const short8*)(bufA + ((4 + i) * 16 + lm) * 32 + sq8);
        if (doSt) stageB(stg, k2);
        __builtin_amdgcn_s_setprio(1);
        #pragma unroll
        for (int i = 0; i < 4; ++i)
            #pragma unroll
            for (int j = 0; j < 4; ++j)
                acc[4 + i][j] = __builtin_amdgcn_mfma_f32_16x16x32_bf16(af[i], bf[j], acc[4 + i][j], 0, 0, 0);
        __builtin_amdgcn_s_setprio(0);

        // ---- ONE sync point per tile: retire tile kt+1's loads, publish ----
        if (kt == NI - 2) { WAITVM0; }
        else if (kt < NI - 2) {
            asm volatile("s_waitcnt vmcnt(6)" ::: "memory");
        }
        __builtin_amdgcn_s_barrier();

        cur = (cur == 2) ? 0 : cur + 1;
    }
    asm volatile("" ::: "memory");

    if constexpr (B16) {
        // ---- coalesced bf16 epilogue: per-wave LDS bounce, PADDED stride 68.
        // wbuf in buf[NI%3]=buf0: last read tile 21, >=2 barriers before here.
        unsigned short* Cb   = (unsigned short*)Cout;
        unsigned short* wbuf = lds + (NI % 3) * BUFS + wave * 1088;   // 16 x 68
        float bvj[4];
        #pragma unroll
        for (int j = 0; j < 4; ++j) bvj[j] = bias[col0 + wave * 64 + j * 16 + lm];
        #pragma unroll
        for (int i = 0; i < 8; ++i) {
            #pragma unroll
            for (int j = 0; j < 4; ++j) {
                #pragma unroll
                for (int r = 0; r < 4; ++r)
                    wbuf[(quad * 4 + r) * 68 + j * 16 + lm] = f32_to_bf16_rn(acc[i][j][r] + bvj[j]);
            }
            asm volatile("s_waitcnt lgkmcnt(0)" ::: "memory");  // cross-lane RAW
            #pragma unroll
            for (int p = 0; p < 2; ++p) {
                const int lrow  = p * 8 + (lane >> 3);
                const int lcol8 = (lane & 7) * 8;
                short8 v = lds_ld8(&wbuf[lrow * 68 + lcol8]);
                *(short8*)(Cb + (size_t)(row0 + i * 16 + lrow) * N +
                           col0 + wave * 64 + lcol8) = v;
            }
            asm volatile("s_waitcnt lgkmcnt(0)" ::: "memory");  // WAR before next i
        }
    } else {
        // ---- fp32 direct epilogue ----
        float* C = (float*)Cout;
        #pragma unroll
        for (int j = 0; j < 4; ++j) {
            const int col = col0 + wave * 64 + j * 16 + lm;
            const float bv = bias[col];
            #pragma unroll
            for (int i = 0; i < 8; ++i) {
                const int rowb = row0 + i * 16 + quad * 4;
                #pragma unroll
                for (int r = 0; r < 4; ++r)
                    C[(size_t)(rowb + r) * N + col] = acc[i][j][r] + bv;
            }
        }
    }
}

// qkv: 64 row-tiles x 9 col-tiles = 576 blocks (%8==0), bijective XCD chunk.
__global__ __launch_bounds__(256, 2)
void gemm_qkv128(const unsigned short* __restrict__ A_g,
                 const unsigned short* __restrict__ B_g,
                 const float* __restrict__ bias,
                 unsigned short* __restrict__ Cb)
{
    __shared__ __align__(16) unsigned short lds[3 * 12288];   // 72 KB
    const int bid = blockIdx.x;
    const int sid = (bid & 7) * 72 + (bid >> 3);              // 576/8 = 72
    const int by  = sid & 63;                                  // row tile
    const int bx  = sid >> 6;                                  // col tile 0..8
    gemm_body_128x256<false, true>(A_g, B_g, bias, Cb,
                                   by * 128, bx * 256, Cdim, C3, lds);
}

// ---------------------------------------------------------------------------
// R19 proj GEMM: BM=128 x BN=128, 48 KB LDS, 3 blocks/CU cap, 384 blocks.
// Same barrier diet: 1 barrier + counted vmcnt(4) per K-tile.
// ---------------------------------------------------------------------------
__global__ __launch_bounds__(256, 3)
void gemm_proj128sq(const unsigned short* __restrict__ AO_g,
                    const unsigned short* __restrict__ B_g,
                    const float* __restrict__ bias,
                    float* __restrict__ C)
{
    constexpr int BK   = 32;
    constexpr int K    = Cdim, N = Cdim;
    constexpr int ABUF = 4096;           // ushorts: A 128x32
    constexpr int BUFS = 8192;           // A 4096 + B 4096 per buffer
    __shared__ __align__(16) unsigned short lds[3 * BUFS];   // 48 KB

    const int tid  = threadIdx.x;
    const int wave = tid >> 6;
    const int lane = tid & 63;
    const int lm   = lane & 15;
    const int quad = lane >> 4;
    const int wy   = wave >> 1, wx = wave & 1;
    const int bid  = blockIdx.x;
    const int sid  = (bid & 7) * 48 + (bid >> 3);            // 384/8 = 48
    const int row0 = (sid & 63) * 128;
    const int col0 = (sid >> 6) * 128;                        // 0..5
    const int NI   = K / BK;             // 24
    const int sq8  = (quad ^ ((lm ^ (lm >> 2)) & 3)) * 8;
    const int sr   = tid >> 2;
    const int sq   = tid & 3;

    floatx4 acc[4][4] = {};

    auto stageA = [&](int buf, int k0) {
        #pragma unroll
        for (int s = 0; s < 2; ++s) {
            const int r  = s * 64 + sr;
            const int gc = ((sq ^ ((r ^ (r >> 2)) & 3)) << 3);
            const int head = k0 >> 6;
            const int off  = (k0 & 63) + gc;
            GLOAD_LDS16(AO_g + (size_t)head * (Mrows * HD) +
                        (size_t)(row0 + r) * HD + off,
                        lds + buf * BUFS + r * 32 + sq * 8);
        }
    };
    auto stageB = [&](int buf, int k0) {
        #pragma unroll
        for (int s = 0; s < 2; ++s) {
            const int r  = s * 64 + sr;
            const int gc = ((sq ^ ((r ^ (r >> 2)) & 3)) << 3);
            GLOAD_LDS16(B_g + (size_t)(col0 + r) * K + k0 + gc,
                        lds + buf * BUFS + ABUF + r * 32 + sq * 8);
        }
    };

    // prologue: tile 0 -> buf0, tile 1 -> buf1  (8 loads in flight)
    stageA(0, 0);  stageB(0, 0);
    stageA(1, BK); stageB(1, BK);
    asm volatile("s_waitcnt vmcnt(4)" ::: "memory");   // tile 0 landed
    __builtin_amdgcn_s_barrier();

    short8 af[4], bf[4];
    int cur = 0;
    for (int kt = 0; kt < NI; ++kt) {
        const unsigned short* bufA = lds + cur * BUFS;
        const unsigned short* bufB = bufA + ABUF;
        const int  stg  = (cur + 2 >= 3) ? cur - 1 : cur + 2;
        const int  k2   = (kt + 2) * BK;
        const bool doSt = (kt + 2 < NI);

        // ---- half 0: all A frags + N half 0 + stageA, MFMA ----
        #pragma unroll
        for (int i = 0; i < 4; ++i)
            af[i] = *(const short8*)(bufA + (wy * 64 + i * 16 + lm) * 32 + sq8);
        #pragma unroll
        for (int j = 0; j < 2; ++j)
            bf[j] = *(const short8*)(bufB + (wx * 64 + j * 16 + lm) * 32 + sq8);
        if (doSt) stageA(stg, k2);
        __builtin_amdgcn_s_setprio(1);
        #pragma unroll
        for (int i = 0; i < 4; ++i)
            #pragma unroll
            for (int j = 0; j < 2; ++j)
                acc[i][j] = __builtin_amdgcn_mfma_f32_16x16x32_bf16(af[i], bf[j], acc[i][j], 0, 0, 0);
        __builtin_amdgcn_s_setprio(0);

        // ---- half 1: N half 1 + stageB, MFMA (af reused) ----
        #pragma unroll
        for (int j = 2; j < 4; ++j)
            bf[j] = *(const short8*)(bufB + (wx * 64 + j * 16 + lm) * 32 + sq8);
        if (doSt) stageB(stg, k2);
        __builtin_amdgcn_s_setprio(1);
        #pragma unroll
        for (int i = 0; i < 4; ++i)
            #pragma unroll
            for (int j = 2; j < 4; ++j)
                acc[i][j] = __builtin_amdgcn_mfma_f32_16x16x32_bf16(af[i], bf[j], acc[i][j], 0, 0, 0);
        __builtin_amdgcn_s_setprio(0);

        // ---- ONE sync point per tile ----
        if (kt == NI - 2) { WAITVM0; }
        else if (kt < NI - 2) {
            asm volatile("s_waitcnt vmcnt(4)" ::: "memory");
        }
        __builtin_amdgcn_s_barrier();

        cur = (cur == 2) ? 0 : cur + 1;
    }
    asm volatile("" ::: "memory");

    // ---- fp32 direct epilogue ----
    #pragma unroll
    for (int j = 0; j < 4; ++j) {
        const int col = col0 + wx * 64 + j * 16 + lm;
        const float bv = bias[col];
        #pragma unroll
        for (int i = 0; i < 4; ++i) {
            const int rowb = row0 + wy * 64 + i * 16 + quad * 4;
            #pragma unroll
            for (int r = 0; r < 4; ++r)
                C[(size_t)(rowb + r) * N + col] = acc[i][j][r] + bv;
        }
    }
}

// ---------------------------------------------------------------------------
// Pure-bf16 MFMA flash attention, R19 = verified R16 register-P structure +
// two latency trims:
//   * incremental prefetch addressing (gcur += 64*C3, mcur += 64) replaces
//     per-tile 64-bit recompute (~25 VALU/tile saved);
//   * lsum split into 2 partial accumulators (halves the 32-long serial
//     fp-add dependency chain; reassociation shifts absmax by ~ulp only).
// ---------------------------------------------------------------------------
__global__ __launch_bounds__(256, 3)
void attn_bf16(const unsigned short* __restrict__ qkv,
               const int* __restrict__ mask,
               unsigned short* __restrict__ outh)
{
    constexpr int LDW = 68;
    constexpr int NT  = Tseq / 64;     // 16 K-tiles
    __shared__ __align__(16) unsigned short Kh[2][64 * LDW];
    __shared__ __align__(16) unsigned short Vh[2][64 * LDW];   // V^T [d][k]
    __shared__ float maskadd[2][64];   // PHYSICAL (swapped) index
    __shared__ int   mflag[2];         // 1 = no masked keys in this tile

    const int tid  = threadIdx.x;
    const int wave = tid >> 6;
    const int lane = tid & 63;
    const int lm   = lane & 15;
    const int quad = lane >> 4;
    const int idx  = blockIdx.x;
    const int bh   = idx % (Bsz * NH);
    const int qb   = idx / (Bsz * NH);
    const int b    = bh / NH;
    const int h    = bh % NH;
    const int q0   = qb * 128;
    const float scale = 0.125f;        // 1/sqrt(64)

    // Q fragments (B-layout: n=lm, k=quad*8+j) straight from global
    short8 qf[2][2];
    #pragma unroll
    for (int mt = 0; mt < 2; ++mt) {
        const size_t qrow = (size_t)(b * Tseq + q0 + wave * 32 + mt * 16 + lm) * C3 + h * HD;
        #pragma unroll
        for (int kf = 0; kf < 2; ++kf)
            qf[mt][kf] = *(const short8*)(qkv + qrow + kf * 32 + quad * 8);
    }

    const int tr0 = (tid & 31) * 2;    // TRUE k-row pair (global load, V col)
    const int sc  = (tid >> 5) * 8;    // 8 dims
    // physical K position: swap bits 3<->4 of the row index
    const int ps0 = (tr0 & 0x27) | ((tr0 & 0x10) >> 1) | ((tr0 & 0x08) << 1);
    const int smi = (tid & 0x27) | ((tid & 0x10) >> 1) | ((tid & 0x08) << 1);

    short8 kh0, kh1, vh0, vh1;
    float  mreg = 0.f;

    // incremental prefetch cursors (tile 0)
    size_t gcur = (size_t)(b * Tseq + tr0) * C3 + Cdim + h * HD + sc;
    int    mcur = b * Tseq + tid;

    // --- prefetch + store tile 0 into buf 0 ---
    {
        kh0 = *(const short8*)(qkv + gcur);
        kh1 = *(const short8*)(qkv + gcur + C3);
        vh0 = *(const short8*)(qkv + gcur + Cdim);
        vh1 = *(const short8*)(qkv + gcur + Cdim + C3);
        lds_st8(&Kh[0][ps0 * LDW + sc], kh0);
        lds_st8(&Kh[0][(ps0 + 1) * LDW + sc], kh1);
        #pragma unroll
        for (int i = 0; i < 8; ++i) {
            unsigned int pv = (unsigned int)(unsigned short)vh0[i] |
                              ((unsigned int)(unsigned short)vh1[i] << 16);
            *(unsigned int*)&Vh[0][(sc + i) * LDW + tr0] = pv;
        }
        if (tid < 64) {
            mreg = (mask[mcur] == 0) ? -1e30f : 0.0f;
            const int f = __all(mreg == 0.0f);
            maskadd[0][smi] = mreg;
            if (tid == 0) mflag[0] = f;
        }
    }
    __syncthreads();

    floatx4 O[2][4] = {};              // [m][d-tile]; lane: q=lm, d=quad*4+r
    float lsA[2] = {0.f, 0.f};         // split lsum chains (reassoc, ~ulp)
    float lsB[2] = {0.f, 0.f};

    for (int kt = 0; kt < NT; ++kt) {
        const int cur = kt & 1;
        const int nxt = cur ^ 1;
        const unsigned short* Khc = Kh[cur];
        const unsigned short* Vhc = Vh[cur];

        // ---- issue prefetch for tile kt+1 early (latency behind compute) ----
        if (kt + 1 < NT) {
            gcur += (size_t)64 * C3;
            mcur += 64;
            kh0 = *(const short8*)(qkv + gcur);
            kh1 = *(const short8*)(qkv + gcur + C3);
            vh0 = *(const short8*)(qkv + gcur + Cdim);
            vh1 = *(const short8*)(qkv + gcur + Cdim + C3);
            if (tid < 64) mreg = (mask[mcur] == 0) ? -1e30f : 0.0f;
        }

        // ---- S^T = K Q^T : D[pos][q], lane: q=lm, pos=quad*4+r (permuted k) ----
        floatx4 S[2][4] = {};
        #pragma unroll
        for (int kf = 0; kf < 2; ++kf) {
            short8 kh[4];
            #pragma unroll
            for (int nt = 0; nt < 4; ++nt)
                kh[nt] = lds_ld8(&Khc[(nt * 16 + lm) * LDW + kf * 32 + quad * 8]);
            #pragma unroll
            for (int mt = 0; mt < 2; ++mt)
                #pragma unroll
                for (int nt = 0; nt < 4; ++nt)
                    S[mt][nt] = __builtin_amdgcn_mfma_f32_16x16x32_bf16(kh[nt], qf[mt][kf], S[mt][nt], 0, 0, 0);
        }

        const int nomask = mflag[cur];   // block-uniform

        // ---- softmax numerator -> packed bf16 pairs in registers ----
        unsigned X[2][8];
        if (nomask) {
            #pragma unroll
            for (int mt = 0; mt < 2; ++mt) {
                #pragma unroll
                for (int nt = 0; nt < 4; ++nt) {
                    float p0 = __expf(S[mt][nt][0] * scale);
                    float p1 = __expf(S[mt][nt][1] * scale);
                    float p2 = __expf(S[mt][nt][2] * scale);
                    float p3 = __expf(S[mt][nt][3] * scale);
                    lsA[mt] += p0; lsB[mt] += p1;
                    lsA[mt] += p2; lsB[mt] += p3;
                    X[mt][nt * 2 + 0] = pack_bf16x2_rn(p0, p1);
                    X[mt][nt * 2 + 1] = pack_bf16x2_rn(p2, p3);
                }
            }
        } else {
            float madd[4][4];
            #pragma unroll
            for (int nt = 0; nt < 4; ++nt)
                #pragma unroll
                for (int r = 0; r < 4; ++r)
                    madd[nt][r] = maskadd[cur][nt * 16 + quad * 4 + r];  // physical
            #pragma unroll
            for (int mt = 0; mt < 2; ++mt) {
                #pragma unroll
                for (int nt = 0; nt < 4; ++nt) {
                    float p0 = __expf(S[mt][nt][0] * scale + madd[nt][0]);
                    float p1 = __expf(S[mt][nt][1] * scale + madd[nt][1]);
                    float p2 = __expf(S[mt][nt][2] * scale + madd[nt][2]);
                    float p3 = __expf(S[mt][nt][3] * scale + madd[nt][3]);
                    lsA[mt] += p0; lsB[mt] += p1;
                    lsA[mt] += p2; lsB[mt] += p3;
                    X[mt][nt * 2 + 0] = pack_bf16x2_rn(p0, p1);
                    X[mt][nt * 2 + 1] = pack_bf16x2_rn(p2, p3);
                }
            }
        }

        // ---- quad exchange: lane-bit4 <-> slot-bit1. ----
        const bool qodd = (quad & 1);
        short8 pf[2][2];
        #pragma unroll
        for (int mt = 0; mt < 2; ++mt) {
            #pragma unroll
            for (int pr = 0; pr < 4; ++pr) {
                const int a  = (pr & 1) | ((pr & 2) << 1);   // 0,1,4,5
                const int b2 = a + 2;
                unsigned t = qodd ? X[mt][a] : X[mt][b2];
                t = (unsigned)__shfl_xor((int)t, 16);
                X[mt][a]  = qodd ? t : X[mt][a];
                X[mt][b2] = qodd ? X[mt][b2] : t;
            }
            uintx4 u0 = {X[mt][0], X[mt][1], X[mt][2], X[mt][3]};
            uintx4 u1 = {X[mt][4], X[mt][5], X[mt][6], X[mt][7]};
            __builtin_memcpy(&pf[mt][0], &u0, 16);
            __builtin_memcpy(&pf[mt][1], &u1, 16);
        }

        // ---- O^T += V^T P^T (P in registers) ----
        #pragma unroll
        for (int kf = 0; kf < 2; ++kf) {
            #pragma unroll
            for (int dt = 0; dt < 4; ++dt) {
                short8 vh = lds_ld8(&Vhc[(dt * 16 + lm) * LDW + kf * 32 + quad * 8]);
                #pragma unroll
                for (int mt = 0; mt < 2; ++mt)
                    O[mt][dt] = __builtin_amdgcn_mfma_f32_16x16x32_bf16(vh, pf[mt][kf], O[mt][dt], 0, 0, 0);
            }
        }

        // ---- store prefetched tile into the other buffer ----
        if (kt + 1 < NT) {
            lds_st8(&Kh[nxt][ps0 * LDW + sc], kh0);
            lds_st8(&Kh[nxt][(ps0 + 1) * LDW + sc], kh1);
            #pragma unroll
            for (int i = 0; i < 8; ++i) {
                unsigned int pv = (unsigned int)(unsigned short)vh0[i] |
                                  ((unsigned int)(unsigned short)vh1[i] << 16);
                *(unsigned int*)&Vh[nxt][(sc + i) * LDW + tr0] = pv;
            }
            if (tid < 64) {
                const int f = __all(mreg == 0.0f);
                maskadd[nxt][smi] = mreg;
                if (tid == 0) mflag[nxt] = f;
            }
        }
        __syncthreads();               // single barrier: orders store->read
    }

    // ---- final l reduction across quads, normalize, head-major write ----
    #pragma unroll
    for (int mt = 0; mt < 2; ++mt) {
        float lsum = lsA[mt] + lsB[mt];
        lsum += __shfl_xor(lsum, 16);
        lsum += __shfl_xor(lsum, 32);
        const float inv_l = 1.0f / lsum;
        const size_t row = (size_t)h * (Mrows * HD) +
                           (size_t)(b * Tseq + q0 + wave * 32 + mt * 16 + lm) * HD;
        #pragma unroll
        for (int dt = 0; dt < 4; ++dt) {
            ushort4 hv;
            unsigned short* hp = &hv.x;
            #pragma unroll
            for (int r = 0; r < 4; ++r)
                hp[r] = f32_to_bf16_rn(O[mt][dt][r] * inv_l);
            *(ushort4*)(outh + row + dt * 16 + quad * 4) = hv;
        }
    }
}

// ---------------------------------------------------------------------------
extern "C" void kernel_launch(void* const* d_in, const int* in_sizes, int n_in,
                              void* d_out, int out_size, void* d_ws, size_t ws_size,
                              hipStream_t stream)
{
    const float* x      = (const float*)d_in[0];
    const int*   mask   = (const int*)  d_in[1];
    const float* W_attn = (const float*)d_in[2];
    const float* b_attn = (const float*)d_in[3];
    const float* W_proj = (const float*)d_in[4];
    const float* b_proj = (const float*)d_in[5];
    float* out = (float*)d_out;

    // workspace (~55 MB)
    unsigned short* xh    = (unsigned short*)d_ws;               // [8192][768]
    unsigned short* wat_h = xh    + (size_t)Mrows * Cdim;        // W_attn^T
    unsigned short* wpt_h = wat_h + (size_t)C3 * Cdim;           // W_proj^T
    unsigned short* qkvh  = wpt_h + (size_t)Cdim * Cdim;         // [8192][2304]
    unsigned short* aoh   = xh;    // reuse: xh dead after gemm1; [12][8192][64]

    dim3 blk(256);

    // merged prep: cast + both transposes, one dispatch (8448 blocks)
    prep_all<<<dim3(8448), blk, 0, stream>>>(x, xh, W_attn, wat_h, W_proj, wpt_h);

    // qkv = x @ W_attn + b_attn  (bf16 out): 64x9 = 576 uniform blocks, 2/CU
    gemm_qkv128<<<dim3(576), blk, 0, stream>>>(xh, wat_h, b_attn, qkvh);

    // attention -> head-major bf16
    attn_bf16<<<dim3((Tseq / 128) * Bsz * NH), blk, 0, stream>>>(qkvh, mask, aoh);

    // out = attnout @ W_proj + b_proj (fp32 out): 64x6 = 384 blocks, 3/CU cap
    gemm_proj128sq<<<dim3(384), blk, 0, stream>>>(aoh, wpt_h, b_proj, out);
}